// Round 6
// baseline (2936.268 us; speedup 1.0000x reference)
//
#include <hip/hip_runtime.h>
#include <hip/hip_bf16.h>
#include <cstdint>
#include <cstddef>

// D = 64 hardcoded (in_feats == hidden == 64).
// CSR/bucket build assumes N <= 131072 (src fits 17 bits; bucket = dst>>8 < 512)
// and E <= 2048*4096 (pscan vals[] capacity).

#define BN_SHIFT 8              // 256 nodes per bucket
#define BN 256
#define NBK 512                 // max bucket count
#define PCHUNK 4096             // edges per hist/part block
#define PCAP 16                 // LDS bin capacity (overflow -> direct exact-slot write)
#define TS 65                   // bagg LDS tile row stride (words); 65%32==1 spreads banks

static __device__ __forceinline__ uint32_t f32_to_bf16_bits(float f) {
    uint32_t u = __builtin_bit_cast(uint32_t, f);
    u += 0x7fffu + ((u >> 16) & 1u);   // RNE (no NaNs in this problem)
    return u >> 16;
}

static __device__ __forceinline__ float bfhi(uint32_t w) {
    return __builtin_bit_cast(float, w);
}

// In-block exclusive scan of bcnt[0..NBK) -> sbb[0..NBK]; 256 threads, 2 elems each.
static __device__ __forceinline__ void scan_bcnt(const int* __restrict__ bcnt,
                                                 int* sbb, int* ssum) {
    int t = threadIdx.x;
    int c0 = bcnt[2 * t], c1 = bcnt[2 * t + 1];
    int v = c0 + c1;
    ssum[t] = v;
    __syncthreads();
    for (int o = 1; o < 256; o <<= 1) {
        int u = (t >= o) ? ssum[t - o] : 0;
        __syncthreads();
        ssum[t] += u;
        __syncthreads();
    }
    int ex = ssum[t] - v;
    sbb[2 * t] = ex;
    sbb[2 * t + 1] = ex + c0;
    if (t == 255) sbb[NBK] = ex + c0 + c1;   // == E
    __syncthreads();
}

// ---------------------------------------------------------------- hist
// Per-block LDS histogram of PCHUNK dsts; dense row write to pcnt. NO global atomics.
__global__ __launch_bounds__(256) void hist_kernel(const int* __restrict__ ei,
                                                   int* __restrict__ pcnt, int E) {
    __shared__ int lc[NBK];
    int tid = threadIdx.x;
    lc[tid] = 0; lc[tid + 256] = 0;
    __syncthreads();

    int e0 = blockIdx.x * PCHUNK;
    int m = min(PCHUNK, E - e0);
    const int* dsts = ei + E + e0;
    if ((((uintptr_t)dsts) & 15) == 0) {
        int m4 = m >> 2;
        for (int t = tid; t < m4; t += 256) {
            int4 d = ((const int4*)dsts)[t];
            atomicAdd(&lc[d.x >> BN_SHIFT], 1);
            atomicAdd(&lc[d.y >> BN_SHIFT], 1);
            atomicAdd(&lc[d.z >> BN_SHIFT], 1);
            atomicAdd(&lc[d.w >> BN_SHIFT], 1);
        }
        for (int i = (m4 << 2) + tid; i < m; i += 256)
            atomicAdd(&lc[dsts[i] >> BN_SHIFT], 1);
    } else {
        for (int i = tid; i < m; i += 256)
            atomicAdd(&lc[dsts[i] >> BN_SHIFT], 1);
    }
    __syncthreads();
    int* row = pcnt + (size_t)blockIdx.x * NBK;
    row[tid] = lc[tid];
    row[tid + 256] = lc[tid + 256];
}

// ---------------------------------------------------------------- pscan
// One block per bucket: exclusive scan of its pcnt column (in place), total -> bcnt.
__global__ __launch_bounds__(256) void pscan_kernel(int* __restrict__ pcnt,
                                                    int* __restrict__ bcnt, int PB) {
    __shared__ int ss[256];
    int b = blockIdx.x;
    int tid = threadIdx.x;
    int iper = (PB + 255) >> 8;          // <= 8 by the E-capacity assumption
    int i0 = tid * iper;
    int i1 = min(PB, i0 + iper);
    int vals[8];
    int s = 0;
    for (int i = i0, k = 0; i < i1; ++i, ++k) {
        vals[k] = pcnt[(size_t)i * NBK + b];
        s += vals[k];
    }
    ss[tid] = s;
    __syncthreads();
    for (int o = 1; o < 256; o <<= 1) {
        int u = (tid >= o) ? ss[tid - o] : 0;
        __syncthreads();
        ss[tid] += u;
        __syncthreads();
    }
    int run = ss[tid] - s;
    for (int i = i0, k = 0; i < i1; ++i, ++k) {
        pcnt[(size_t)i * NBK + b] = run;
        run += vals[k];
    }
    if (tid == 255) bcnt[b] = ss[255];
}

// ---------------------------------------------------------------- partition
// Deterministic exact-slot partition: base = bbase(in-block scan) + poff[blk][b].
// pack = src | (dstoff << 17). NO global atomics, no bscan kernel.
__global__ __launch_bounds__(256) void part_kernel(const int* __restrict__ ei,
                                                   const int* __restrict__ bcnt,
                                                   const int* __restrict__ poff,
                                                   uint32_t* __restrict__ stage, int E) {
    __shared__ int sbb[NBK + 1];
    __shared__ int ssum[256];
    __shared__ int cnt[NBK];
    __shared__ int base[NBK];
    __shared__ uint32_t bins[NBK * PCAP];   // 32 KB
    int tid = threadIdx.x;
    scan_bcnt(bcnt, sbb, ssum);

    cnt[tid] = 0; cnt[tid + 256] = 0;
    {
        const int* prow = poff + (size_t)blockIdx.x * NBK;
        base[tid] = sbb[tid] + prow[tid];
        base[tid + 256] = sbb[tid + 256] + prow[tid + 256];
    }
    __syncthreads();

    int e0 = blockIdx.x * PCHUNK;
#pragma unroll
    for (int k = 0; k < PCHUNK / 256; ++k) {
        int e = e0 + (k << 8) + tid;
        if (e < E) {
            int s = ei[e];
            int d = ei[E + e];
            int b = d >> BN_SHIFT;
            uint32_t pack = (uint32_t)s | ((uint32_t)(d & (BN - 1)) << 17);
            int pos = atomicAdd(&cnt[b], 1);
            if (pos < PCAP) bins[b * PCAP + pos] = pack;
            else stage[base[b] + pos] = pack;     // exact slot, race-free
        }
    }
    __syncthreads();

    // flush: each wave handles 4 bins at a time (16 lanes per bin)
    int wave = tid >> 6, lane = tid & 63;
    int sub = lane >> 4, idx = lane & 15;
    for (int b0 = wave * 4; b0 < NBK; b0 += 16) {
        int b = b0 + sub;
        int c = min(cnt[b], PCAP);
        if (idx < c) stage[base[b] + idx] = bins[b * PCAP + idx];
    }
}

// ---------------------------------------------------------------- ndeg
// One block per bucket: LDS histogram of stage dstoffs -> dis = rsqrt(deg+1).
__global__ __launch_bounds__(256) void ndeg_kernel(const uint32_t* __restrict__ stage,
                                                   const int* __restrict__ bcnt,
                                                   float* __restrict__ dis, int n) {
    __shared__ int sbb[NBK + 1];
    __shared__ int ssum[256];
    __shared__ int cnt[BN];
    int tid = threadIdx.x;
    scan_bcnt(bcnt, sbb, ssum);
    int b = blockIdx.x;
    int ebase = sbb[b];
    int ecnt = sbb[b + 1] - ebase;
    cnt[tid] = 0;
    __syncthreads();
    for (int i = tid; i < ecnt; i += 256)
        atomicAdd(&cnt[stage[ebase + i] >> 17], 1);
    __syncthreads();
    int node = (b << BN_SHIFT) + tid;
    if (node < n) dis[node] = rsqrtf((float)(cnt[tid] + 1));  // +1 self-loop
}

// ---------------------------------------------------------------- GEMM [N,64]@[64,64]
// MODE 0: out = bf16( (x@W) * dis[row] );  MODE 1: out = fp32( (x@W) + bias )
template <int MODE>
__global__ __launch_bounds__(256) void gemm_kernel(const float* __restrict__ x,
                                                   const float* __restrict__ W,
                                                   const float* __restrict__ dis,
                                                   const float* __restrict__ bias,
                                                   void* __restrict__ out, int n) {
    __shared__ float Wl[64 * 64];
    int t = threadIdx.x;
    {
        const float4* W4 = (const float4*)W;
        float4* Wl4 = (float4*)Wl;
#pragma unroll
        for (int i = 0; i < 4; ++i) Wl4[t + i * 256] = W4[t + i * 256];
    }
    __syncthreads();

    int row = blockIdx.x * 256 + t;
    if (row >= n) return;

    const float4* xr = (const float4*)(x + (size_t)row * 64);
    float4 acc4[16];
#pragma unroll
    for (int p = 0; p < 16; ++p) acc4[p] = make_float4(0.f, 0.f, 0.f, 0.f);

    float4 xq = xr[0];
    for (int k4 = 0; k4 < 16; ++k4) {
        float4 xn = xq;
        if (k4 < 15) xn = xr[k4 + 1];
        float xs[4] = {xq.x, xq.y, xq.z, xq.w};
#pragma unroll
        for (int kk = 0; kk < 4; ++kk) {
            float xk = xs[kk];
            const float4* wr = (const float4*)&Wl[((k4 << 2) + kk) << 6];
#pragma unroll
            for (int j4 = 0; j4 < 16; ++j4) {
                float4 wv = wr[j4];
                acc4[j4].x = fmaf(xk, wv.x, acc4[j4].x);
                acc4[j4].y = fmaf(xk, wv.y, acc4[j4].y);
                acc4[j4].z = fmaf(xk, wv.z, acc4[j4].z);
                acc4[j4].w = fmaf(xk, wv.w, acc4[j4].w);
            }
        }
        xq = xn;
    }

    if (MODE == 0) {
        float s = dis[row];
        uint4* go = (uint4*)out;
#pragma unroll
        for (int p = 0; p < 8; ++p) {
            float4 a = acc4[2 * p];
            float4 bq = acc4[2 * p + 1];
            uint4 o;
            o.x = (f32_to_bf16_bits(a.y * s) << 16) | f32_to_bf16_bits(a.x * s);
            o.y = (f32_to_bf16_bits(a.w * s) << 16) | f32_to_bf16_bits(a.z * s);
            o.z = (f32_to_bf16_bits(bq.y * s) << 16) | f32_to_bf16_bits(bq.x * s);
            o.w = (f32_to_bf16_bits(bq.w * s) << 16) | f32_to_bf16_bits(bq.z * s);
            go[(size_t)row * 8 + p] = o;
        }
    } else {
        const float4* b4 = (const float4*)bias;
        float4* fo = (float4*)out;
#pragma unroll
        for (int p = 0; p < 16; ++p) {
            float4 bb = b4[p];
            float4 a = acc4[p];
            a.x += bb.x; a.y += bb.y; a.z += bb.z; a.w += bb.w;
            fo[(size_t)row * 16 + p] = a;
        }
    }
}

// ---------------------------------------------------------------- bucket-push aggregation
// One block per 256-node bucket. LDS fp32 out-tile (stride 65 words), stream the
// bucket's packed edges from stage, gather g[src] (bf16 128B rows), ds_add_f32
// accumulate. Epilogue adds self term, scales by dis, bias+relu, dense write.
__global__ __launch_bounds__(256) void bagg_kernel(const char* __restrict__ g,
                                                   const uint32_t* __restrict__ stage,
                                                   const int* __restrict__ bcnt,
                                                   const float* __restrict__ dis,
                                                   const float* __restrict__ bias,
                                                   float* __restrict__ out, int n) {
    __shared__ int sbb[NBK + 1];
    __shared__ int ssum[256];
    __shared__ float tile[BN * TS];          // 66,560 B
    int tid = threadIdx.x;
    scan_bcnt(bcnt, sbb, ssum);
    int b = blockIdx.x;
    int node0 = b << BN_SHIFT;
    int ebase = sbb[b];
    int eend = sbb[b + 1];

    for (int i = tid; i < BN * TS; i += 256) tile[i] = 0.f;
    __syncthreads();

    int wave = tid >> 6, lane = tid & 63;
    int grp = lane >> 3, chk = lane & 7;
    const char* gc = g + (chk << 4);         // this lane's 16B feature chunk
    int chkw = chk << 3;                     // word offset of features

    int e = ebase + (wave << 3) + grp;       // waves interleave by 8, groups by 1
    for (; e + 32 < eend; e += 64) {         // unroll x2 (2 outstanding gathers/lane)
        uint32_t pk0 = stage[e];
        uint32_t pk1 = stage[e + 32];
        uint4 q0 = *(const uint4*)(gc + ((pk0 & 0x1ffff) << 7));
        uint4 q1 = *(const uint4*)(gc + ((pk1 & 0x1ffff) << 7));
        float* t0 = &tile[(pk0 >> 17) * TS + chkw];
        atomicAdd(t0 + 0, bfhi(q0.x << 16)); atomicAdd(t0 + 1, bfhi(q0.x & 0xffff0000u));
        atomicAdd(t0 + 2, bfhi(q0.y << 16)); atomicAdd(t0 + 3, bfhi(q0.y & 0xffff0000u));
        atomicAdd(t0 + 4, bfhi(q0.z << 16)); atomicAdd(t0 + 5, bfhi(q0.z & 0xffff0000u));
        atomicAdd(t0 + 6, bfhi(q0.w << 16)); atomicAdd(t0 + 7, bfhi(q0.w & 0xffff0000u));
        float* t1 = &tile[(pk1 >> 17) * TS + chkw];
        atomicAdd(t1 + 0, bfhi(q1.x << 16)); atomicAdd(t1 + 1, bfhi(q1.x & 0xffff0000u));
        atomicAdd(t1 + 2, bfhi(q1.y << 16)); atomicAdd(t1 + 3, bfhi(q1.y & 0xffff0000u));
        atomicAdd(t1 + 4, bfhi(q1.z << 16)); atomicAdd(t1 + 5, bfhi(q1.z & 0xffff0000u));
        atomicAdd(t1 + 6, bfhi(q1.w << 16)); atomicAdd(t1 + 7, bfhi(q1.w & 0xffff0000u));
    }
    for (; e < eend; e += 32) {
        uint32_t pk = stage[e];
        uint4 q = *(const uint4*)(gc + ((pk & 0x1ffff) << 7));
        float* t0 = &tile[(pk >> 17) * TS + chkw];
        atomicAdd(t0 + 0, bfhi(q.x << 16)); atomicAdd(t0 + 1, bfhi(q.x & 0xffff0000u));
        atomicAdd(t0 + 2, bfhi(q.y << 16)); atomicAdd(t0 + 3, bfhi(q.y & 0xffff0000u));
        atomicAdd(t0 + 4, bfhi(q.z << 16)); atomicAdd(t0 + 5, bfhi(q.z & 0xffff0000u));
        atomicAdd(t0 + 6, bfhi(q.w << 16)); atomicAdd(t0 + 7, bfhi(q.w & 0xffff0000u));
    }
    __syncthreads();

    // epilogue: wave w handles nodes [w*64, w*64+64); lane = feature
    float bl = bias[lane];
#pragma unroll 4
    for (int j = 0; j < 64; ++j) {
        int nd = (wave << 6) + j;
        int node = node0 + nd;
        if (node >= n) break;
        float acc = tile[nd * TS + lane];
        uint32_t sf = ((const ushort*)(g + ((size_t)node << 7)))[lane];
        acc += bfhi(sf << 16);               // self term (g already has dis[node])
        float v = fmaxf(fmaf(acc, dis[node], bl), 0.f);
        out[(size_t)node * 64 + lane] = v;
    }
}

// ---------------------------------------------------------------- launch
extern "C" void kernel_launch(void* const* d_in, const int* in_sizes, int n_in,
                              void* d_out, int out_size, void* d_ws, size_t ws_size,
                              hipStream_t stream) {
    const float* x  = (const float*)d_in[0];
    const int*   ei = (const int*)d_in[1];
    const float* W1 = (const float*)d_in[2];
    const float* b1 = (const float*)d_in[3];
    const float* W2 = (const float*)d_in[4];
    const float* b2 = (const float*)d_in[5];
    // Wq/bq/Wk/bk dead: softmax over a length-1 axis is identity.
    const float* Wv = (const float*)d_in[10];
    const float* bv = (const float*)d_in[11];

    const int N = in_sizes[0] / 64;
    const int E = in_sizes[1] / 2;
    const int NB = (N + BN - 1) >> BN_SHIFT;
    const int PB = (E + PCHUNK - 1) / PCHUNK;

    auto align_up = [](size_t v) { return (v + 255) & ~(size_t)255; };
    char* p = (char*)d_ws;
    float* dis    = (float*)p;       p += align_up((size_t)N * 4);
    int*   pcnt   = (int*)p;         p += align_up((size_t)PB * NBK * 4);
    int*   bcnt   = (int*)p;         p += align_up((size_t)NBK * 4);
    uint32_t* stage = (uint32_t*)p;  p += align_up((size_t)E * 4);   // persists (no alias now)
    char*  gbuf   = p;               p += align_up((size_t)N * 128); // bf16 rows
    float* xbuf   = (float*)p;       p += align_up((size_t)N * 256); // fp32 hidden

    int nbl = (N + 255) / 256;

    hist_kernel <<<PB, 256, 0, stream>>>(ei, pcnt, E);
    pscan_kernel<<<NBK, 256, 0, stream>>>(pcnt, bcnt, PB);
    part_kernel <<<PB, 256, 0, stream>>>(ei, bcnt, pcnt, stage, E);
    ndeg_kernel <<<NB, 256, 0, stream>>>(stage, bcnt, dis, N);

    // layer 1: g = bf16(dis * (x@W1)); xbuf = relu(dis*(Agg(g)+self) + b1)
    gemm_kernel<0><<<nbl, 256, 0, stream>>>(x, W1, dis, nullptr, gbuf, N);
    bagg_kernel<<<NB, 256, 0, stream>>>(gbuf, stage, bcnt, dis, b1, xbuf, N);

    // layer 2
    gemm_kernel<0><<<nbl, 256, 0, stream>>>(xbuf, W2, dis, nullptr, gbuf, N);
    bagg_kernel<<<NB, 256, 0, stream>>>(gbuf, stage, bcnt, dis, b2, xbuf, N);

    // output: v = xbuf@Wv + bv (attention identity at seq_len 1)
    gemm_kernel<1><<<nbl, 256, 0, stream>>>(xbuf, Wv, nullptr, bv, d_out, N);
}

// Round 7
// 367.185 us; speedup vs baseline: 7.9967x; 7.9967x over previous
//
#include <hip/hip_runtime.h>
#include <hip/hip_bf16.h>
#include <cstdint>
#include <cstddef>

// D = 64 hardcoded (in_feats == hidden == 64).
// CSR build assumes N <= 131072 (src fits 17 bits; bucket = dst>>8 < 512)
// and E <= 2048*4096 (pscan vals[] capacity).

#define BN_SHIFT 8              // 256 nodes per bucket
#define BN 256
#define NBK 512                 // max bucket count
#define PCHUNK 4096             // edges per hist/part block
#define PCAP 16                 // LDS bin capacity (overflow -> direct exact-slot write)
#define BCAP 10240              // build LDS edge capacity (mean 8192, +22 sigma; fallback ok)

static __device__ __forceinline__ uint32_t f32_to_bf16_bits(float f) {
    uint32_t u = __builtin_bit_cast(uint32_t, f);
    u += 0x7fffu + ((u >> 16) & 1u);   // RNE (no NaNs in this problem)
    return u >> 16;
}

static __device__ __forceinline__ void add_bf16x8(float* acc, uint4 q) {
    uint32_t w0 = q.x, w1 = q.y, w2 = q.z, w3 = q.w;
    acc[0] += __builtin_bit_cast(float, w0 << 16);
    acc[1] += __builtin_bit_cast(float, w0 & 0xffff0000u);
    acc[2] += __builtin_bit_cast(float, w1 << 16);
    acc[3] += __builtin_bit_cast(float, w1 & 0xffff0000u);
    acc[4] += __builtin_bit_cast(float, w2 << 16);
    acc[5] += __builtin_bit_cast(float, w2 & 0xffff0000u);
    acc[6] += __builtin_bit_cast(float, w3 << 16);
    acc[7] += __builtin_bit_cast(float, w3 & 0xffff0000u);
}

// In-block exclusive scan of bcnt[0..NBK) -> sbb[0..NBK]; 256 threads, 2 elems each.
static __device__ __forceinline__ void scan_bcnt(const int* __restrict__ bcnt,
                                                 int* sbb, int* ssum) {
    int t = threadIdx.x;
    int c0 = bcnt[2 * t], c1 = bcnt[2 * t + 1];
    int v = c0 + c1;
    ssum[t] = v;
    __syncthreads();
    for (int o = 1; o < 256; o <<= 1) {
        int u = (t >= o) ? ssum[t - o] : 0;
        __syncthreads();
        ssum[t] += u;
        __syncthreads();
    }
    int ex = ssum[t] - v;
    sbb[2 * t] = ex;
    sbb[2 * t + 1] = ex + c0;
    if (t == 255) sbb[NBK] = ex + c0 + c1;   // == E
    __syncthreads();
}

// ---------------------------------------------------------------- hist
// Per-block LDS histogram of PCHUNK dsts; dense row write to pcnt. NO global atomics.
__global__ __launch_bounds__(256) void hist_kernel(const int* __restrict__ ei,
                                                   int* __restrict__ pcnt, int E) {
    __shared__ int lc[NBK];
    int tid = threadIdx.x;
    lc[tid] = 0; lc[tid + 256] = 0;
    __syncthreads();

    int e0 = blockIdx.x * PCHUNK;
    int m = min(PCHUNK, E - e0);
    const int* dsts = ei + E + e0;
    if ((((uintptr_t)dsts) & 15) == 0) {
        int m4 = m >> 2;
        for (int t = tid; t < m4; t += 256) {
            int4 d = ((const int4*)dsts)[t];
            atomicAdd(&lc[d.x >> BN_SHIFT], 1);
            atomicAdd(&lc[d.y >> BN_SHIFT], 1);
            atomicAdd(&lc[d.z >> BN_SHIFT], 1);
            atomicAdd(&lc[d.w >> BN_SHIFT], 1);
        }
        for (int i = (m4 << 2) + tid; i < m; i += 256)
            atomicAdd(&lc[dsts[i] >> BN_SHIFT], 1);
    } else {
        for (int i = tid; i < m; i += 256)
            atomicAdd(&lc[dsts[i] >> BN_SHIFT], 1);
    }
    __syncthreads();
    int* row = pcnt + (size_t)blockIdx.x * NBK;
    row[tid] = lc[tid];
    row[tid + 256] = lc[tid + 256];
}

// ---------------------------------------------------------------- pscan
// One block per bucket: exclusive scan of its pcnt column (in place), total -> bcnt.
__global__ __launch_bounds__(256) void pscan_kernel(int* __restrict__ pcnt,
                                                    int* __restrict__ bcnt, int PB) {
    __shared__ int ss[256];
    int b = blockIdx.x;
    int tid = threadIdx.x;
    int iper = (PB + 255) >> 8;          // <= 8 by the E-capacity assumption
    int i0 = tid * iper;
    int i1 = min(PB, i0 + iper);
    int vals[8];
    int s = 0;
    for (int i = i0, k = 0; i < i1; ++i, ++k) {
        vals[k] = pcnt[(size_t)i * NBK + b];
        s += vals[k];
    }
    ss[tid] = s;
    __syncthreads();
    for (int o = 1; o < 256; o <<= 1) {
        int u = (tid >= o) ? ss[tid - o] : 0;
        __syncthreads();
        ss[tid] += u;
        __syncthreads();
    }
    int run = ss[tid] - s;
    for (int i = i0, k = 0; i < i1; ++i, ++k) {
        pcnt[(size_t)i * NBK + b] = run;
        run += vals[k];
    }
    if (tid == 255) bcnt[b] = ss[255];
}

// ---------------------------------------------------------------- partition
// Deterministic exact-slot partition: base = sbb(in-block scan of bcnt) + poff[blk][b].
// pack = src | (dstoff << 17). NO global atomics.
__global__ __launch_bounds__(256) void part_kernel(const int* __restrict__ ei,
                                                   const int* __restrict__ bcnt,
                                                   const int* __restrict__ poff,
                                                   uint32_t* __restrict__ stage, int E) {
    __shared__ int sbb[NBK + 1];
    __shared__ int ssum[256];
    __shared__ int cnt[NBK];
    __shared__ int base[NBK];
    __shared__ uint32_t bins[NBK * PCAP];   // 32 KB
    int tid = threadIdx.x;
    scan_bcnt(bcnt, sbb, ssum);

    cnt[tid] = 0; cnt[tid + 256] = 0;
    {
        const int* prow = poff + (size_t)blockIdx.x * NBK;
        base[tid] = sbb[tid] + prow[tid];
        base[tid + 256] = sbb[tid + 256] + prow[tid + 256];
    }
    __syncthreads();

    int e0 = blockIdx.x * PCHUNK;
#pragma unroll
    for (int k = 0; k < PCHUNK / 256; ++k) {
        int e = e0 + (k << 8) + tid;
        if (e < E) {
            int s = ei[e];
            int d = ei[E + e];
            int b = d >> BN_SHIFT;
            uint32_t pack = (uint32_t)s | ((uint32_t)(d & (BN - 1)) << 17);
            int pos = atomicAdd(&cnt[b], 1);
            if (pos < PCAP) bins[b * PCAP + pos] = pack;
            else stage[base[b] + pos] = pack;     // exact slot, race-free
        }
    }
    __syncthreads();

    // flush: each wave handles 4 bins at a time (16 lanes per bin)
    int wave = tid >> 6, lane = tid & 63;
    int sub = lane >> 4, idx = lane & 15;
    for (int b0 = wave * 4; b0 < NBK; b0 += 16) {
        int b = b0 + sub;
        int c = min(cnt[b], PCAP);
        if (idx < c) stage[base[b] + idx] = bins[b * PCAP + idx];
    }
}

// ---------------------------------------------------------------- build
// One block per bucket. Self-loop folded at slot 0; col holds byte offsets (src*128).
__global__ __launch_bounds__(256) void build_kernel(const uint32_t* __restrict__ stage,
                                                    const int* __restrict__ bcnt,
                                                    int* __restrict__ rowptr,
                                                    float* __restrict__ dis,
                                                    int* __restrict__ col, int n) {
    __shared__ int sbb[NBK + 1];
    __shared__ uint32_t eb[BCAP];            // 40 KB
    __shared__ int cnt[BN];
    __shared__ int off[BN];
    __shared__ int cur[BN];
    __shared__ int ssum[256];
    int tid = threadIdx.x;
    scan_bcnt(bcnt, sbb, ssum);
    int b = blockIdx.x;
    int node0 = b << BN_SHIFT;
    int ebase = sbb[b];
    int ecnt = sbb[b + 1] - ebase;
    int colbase = ebase + node0;             // prior buckets' edges + self slots

    cnt[tid] = 0;
    cur[tid] = 0;
    __syncthreads();

    bool fits = (ecnt <= BCAP);
    for (int i = tid; i < ecnt; i += 256) {
        uint32_t pk = stage[ebase + i];
        if (fits) eb[i] = pk;
        atomicAdd(&cnt[pk >> 17], 1);
    }
    __syncthreads();

    int c = cnt[tid] + 1;                    // + self slot
    ssum[tid] = c;
    __syncthreads();
    for (int o = 1; o < 256; o <<= 1) {
        int u = (tid >= o) ? ssum[tid - o] : 0;
        __syncthreads();
        ssum[tid] += u;
        __syncthreads();
    }
    int ex = ssum[tid] - c;
    off[tid] = ex;
    int node = node0 + tid;
    if (node <= n) rowptr[node] = colbase + ex;   // single writer for every entry incl. n
    if (node < n) {
        dis[node] = rsqrtf((float)c);        // c = deg+1 (self)
        col[colbase + ex] = node << 7;       // self edge, byte offset
    }
    __syncthreads();

    if (fits) {
        for (int i = tid; i < ecnt; i += 256) {
            uint32_t pk = eb[i];
            int doff = pk >> 17;
            int p = atomicAdd(&cur[doff], 1);
            col[colbase + off[doff] + 1 + p] = (int)(pk & 0x1ffff) << 7;
        }
    } else {
        for (int i = tid; i < ecnt; i += 256) {
            uint32_t pk = stage[ebase + i];
            int doff = pk >> 17;
            int p = atomicAdd(&cur[doff], 1);
            col[colbase + off[doff] + 1 + p] = (int)(pk & 0x1ffff) << 7;
        }
    }
}

// ---------------------------------------------------------------- GEMM [N,64]@[64,64]
// MODE 0: out = bf16( (x@W) * dis[row] );  MODE 1: out = fp32( (x@W) + bias )
template <int MODE>
__global__ __launch_bounds__(256) void gemm_kernel(const float* __restrict__ x,
                                                   const float* __restrict__ W,
                                                   const float* __restrict__ dis,
                                                   const float* __restrict__ bias,
                                                   void* __restrict__ out, int n) {
    __shared__ float Wl[64 * 64];
    int t = threadIdx.x;
    {
        const float4* W4 = (const float4*)W;
        float4* Wl4 = (float4*)Wl;
#pragma unroll
        for (int i = 0; i < 4; ++i) Wl4[t + i * 256] = W4[t + i * 256];
    }
    __syncthreads();

    int row = blockIdx.x * 256 + t;
    if (row >= n) return;

    const float4* xr = (const float4*)(x + (size_t)row * 64);
    float4 acc4[16];
#pragma unroll
    for (int p = 0; p < 16; ++p) acc4[p] = make_float4(0.f, 0.f, 0.f, 0.f);

    float4 xq = xr[0];
    for (int k4 = 0; k4 < 16; ++k4) {
        float4 xn = xq;
        if (k4 < 15) xn = xr[k4 + 1];
        float xs[4] = {xq.x, xq.y, xq.z, xq.w};
#pragma unroll
        for (int kk = 0; kk < 4; ++kk) {
            float xk = xs[kk];
            const float4* wr = (const float4*)&Wl[((k4 << 2) + kk) << 6];
#pragma unroll
            for (int j4 = 0; j4 < 16; ++j4) {
                float4 wv = wr[j4];
                acc4[j4].x = fmaf(xk, wv.x, acc4[j4].x);
                acc4[j4].y = fmaf(xk, wv.y, acc4[j4].y);
                acc4[j4].z = fmaf(xk, wv.z, acc4[j4].z);
                acc4[j4].w = fmaf(xk, wv.w, acc4[j4].w);
            }
        }
        xq = xn;
    }

    if (MODE == 0) {
        float s = dis[row];
        uint4* go = (uint4*)out;
#pragma unroll
        for (int p = 0; p < 8; ++p) {
            float4 a = acc4[2 * p];
            float4 bq = acc4[2 * p + 1];
            uint4 o;
            o.x = (f32_to_bf16_bits(a.y * s) << 16) | f32_to_bf16_bits(a.x * s);
            o.y = (f32_to_bf16_bits(a.w * s) << 16) | f32_to_bf16_bits(a.z * s);
            o.z = (f32_to_bf16_bits(bq.y * s) << 16) | f32_to_bf16_bits(bq.x * s);
            o.w = (f32_to_bf16_bits(bq.w * s) << 16) | f32_to_bf16_bits(bq.z * s);
            go[(size_t)row * 8 + p] = o;
        }
    } else {
        const float4* b4 = (const float4*)bias;
        float4* fo = (float4*)out;
#pragma unroll
        for (int p = 0; p < 16; ++p) {
            float4 bb = b4[p];
            float4 a = acc4[p];
            a.x += bb.x; a.y += bb.y; a.z += bb.z; a.w += bb.w;
            fo[(size_t)row * 16 + p] = a;
        }
    }
}

// ---------------------------------------------------------------- pull aggregation
// Each 8-lane group owns ONE node (8 nodes/wave, 32/block): lanes split the 64
// features (16B chunk each), iterate the node's edges sequentially. No cross-lane
// reduce. col holds byte offsets (src*128), self-loop at slot 0.
__global__ __launch_bounds__(256) void agg_kernel(const char* __restrict__ g,
                                                  const int* __restrict__ rowptr,
                                                  const int* __restrict__ col,
                                                  const float* __restrict__ dis,
                                                  const float* __restrict__ bias,
                                                  float* __restrict__ out, int n) {
    int tid = threadIdx.x;
    int wave = tid >> 6, lane = tid & 63;
    int grp = lane >> 3, chk = lane & 7;
    int node = blockIdx.x * 32 + (wave << 3) + grp;
    if (node >= n) return;

    const char* gc = g + (chk << 4);         // this lane's 16B feature chunk

    float acc[8];
#pragma unroll
    for (int j = 0; j < 8; ++j) acc[j] = 0.f;

    int e = rowptr[node];                    // broadcast within group
    int end = rowptr[node + 1];
    for (; e + 1 < end; e += 2) {
        int o0 = col[e];
        int o1 = col[e + 1];
        uint4 q0 = *(const uint4*)(gc + o0);
        uint4 q1 = *(const uint4*)(gc + o1);
        add_bf16x8(acc, q0);
        add_bf16x8(acc, q1);
    }
    if (e < end) add_bf16x8(acc, *(const uint4*)(gc + col[e]));

    float dv = dis[node];
    const float4* b4 = (const float4*)bias;
    float4 bb0 = b4[chk * 2], bb1 = b4[chk * 2 + 1];
    float4 o0, o1;
    o0.x = fmaxf(fmaf(acc[0], dv, bb0.x), 0.f);
    o0.y = fmaxf(fmaf(acc[1], dv, bb0.y), 0.f);
    o0.z = fmaxf(fmaf(acc[2], dv, bb0.z), 0.f);
    o0.w = fmaxf(fmaf(acc[3], dv, bb0.w), 0.f);
    o1.x = fmaxf(fmaf(acc[4], dv, bb1.x), 0.f);
    o1.y = fmaxf(fmaf(acc[5], dv, bb1.y), 0.f);
    o1.z = fmaxf(fmaf(acc[6], dv, bb1.z), 0.f);
    o1.w = fmaxf(fmaf(acc[7], dv, bb1.w), 0.f);
    float4* fo = (float4*)(out + (size_t)node * 64 + (chk << 3));
    fo[0] = o0;
    fo[1] = o1;
}

// ---------------------------------------------------------------- launch
extern "C" void kernel_launch(void* const* d_in, const int* in_sizes, int n_in,
                              void* d_out, int out_size, void* d_ws, size_t ws_size,
                              hipStream_t stream) {
    const float* x  = (const float*)d_in[0];
    const int*   ei = (const int*)d_in[1];
    const float* W1 = (const float*)d_in[2];
    const float* b1 = (const float*)d_in[3];
    const float* W2 = (const float*)d_in[4];
    const float* b2 = (const float*)d_in[5];
    // Wq/bq/Wk/bk dead: softmax over a length-1 axis is identity.
    const float* Wv = (const float*)d_in[10];
    const float* bv = (const float*)d_in[11];

    const int N = in_sizes[0] / 64;
    const int E = in_sizes[1] / 2;
    const int NB = (N + BN - 1) >> BN_SHIFT;
    const int PB = (E + PCHUNK - 1) / PCHUNK;

    auto align_up = [](size_t v) { return (v + 255) & ~(size_t)255; };
    char* p = (char*)d_ws;
    int*   rowptr = (int*)p;    p += align_up((size_t)(N + 1) * 4);
    float* dis    = (float*)p;  p += align_up((size_t)N * 4);
    int*   pcnt   = (int*)p;    p += align_up((size_t)PB * NBK * 4);
    int*   bcnt   = (int*)p;    p += align_up((size_t)NBK * 4);
    int*   col    = (int*)p;    p += align_up((size_t)(E + N + BN) * 4);
    size_t gsz    = (size_t)N * 128 > (size_t)E * 4 ? (size_t)N * 128 : (size_t)E * 4;
    char*  gbuf   = p;          p += align_up(gsz);              // bf16 rows; stage alias
    float* xbuf   = (float*)p;  p += align_up((size_t)N * 256);  // fp32 hidden
    uint32_t* stage = (uint32_t*)gbuf;   // dead before first gemm writes gbuf

    int nbl = (N + 255) / 256;
    int abl = (N + 31) / 32;    // 32 nodes per block (8-lane group per node)

    hist_kernel <<<PB, 256, 0, stream>>>(ei, pcnt, E);
    pscan_kernel<<<NBK, 256, 0, stream>>>(pcnt, bcnt, PB);
    part_kernel <<<PB, 256, 0, stream>>>(ei, bcnt, pcnt, stage, E);
    build_kernel<<<NB, 256, 0, stream>>>(stage, bcnt, rowptr, dis, col, N);

    // layer 1: g = bf16(dis * (x@W1)); xbuf = relu(dis*Agg(g) + b1)
    gemm_kernel<0><<<nbl, 256, 0, stream>>>(x, W1, dis, nullptr, gbuf, N);
    agg_kernel<<<abl, 256, 0, stream>>>(gbuf, rowptr, col, dis, b1, xbuf, N);

    // layer 2
    gemm_kernel<0><<<nbl, 256, 0, stream>>>(xbuf, W2, dis, nullptr, gbuf, N);
    agg_kernel<<<abl, 256, 0, stream>>>(gbuf, rowptr, col, dis, b2, xbuf, N);

    // output: v = xbuf@Wv + bv (attention identity at seq_len 1)
    gemm_kernel<1><<<nbl, 256, 0, stream>>>(xbuf, Wv, nullptr, bv, d_out, N);
}